// Round 11
// baseline (1030.859 us; speedup 1.0000x reference)
//
#include <hip/hip_runtime.h>

#define MDIM 128
#define NCOL 20000
#define NEDGE 320000
#define NITER 30
#define FKAPPA 0.99f

typedef unsigned int uint;
typedef unsigned short ushort;
typedef __attribute__((ext_vector_type(8))) short short8;
typedef __attribute__((ext_vector_type(4))) float f32x4;

__device__ __forceinline__ float bf2f(ushort b){
    uint u = ((uint)b) << 16;
    return __builtin_bit_cast(float, u);
}
__device__ __forceinline__ ushort f2bf(float f){
    uint u = __builtin_bit_cast(uint, f);
    uint r = (u + 0x7fffu + ((u >> 16) & 1u)) >> 16;
    return (ushort)r;
}
__device__ __forceinline__ uint pack2(float a, float b){
    return (uint)f2bf(a) | ((uint)f2bf(b) << 16);
}

// ---------------- CSC build ----------------
__global__ void k_zero(int* __restrict__ p){
    int i = blockIdx.x * 256 + threadIdx.x;
    if (i < 2 * NCOL) p[i] = 0;
}

__global__ void k_hist(const int* __restrict__ cols, int* __restrict__ cnt){
    int e = blockIdx.x * 256 + threadIdx.x;
    if (e < NEDGE) atomicAdd(&cnt[cols[e]], 1);
}

__global__ void k_scan(const int* __restrict__ cnt, int* __restrict__ start){
    __shared__ int lds[256];
    const int SEG = (NCOL + 255) / 256; // 79
    int t = threadIdx.x;
    int lo = t * SEG;
    int hi = min(lo + SEG, NCOL);
    int s = 0;
    for (int i = lo; i < hi; ++i) s += cnt[i];
    lds[t] = s;
    __syncthreads();
    for (int off = 1; off < 256; off <<= 1){
        int v = (t >= off) ? lds[t - off] : 0;
        __syncthreads();
        lds[t] += v;
        __syncthreads();
    }
    int run = (t > 0) ? lds[t - 1] : 0;
    for (int i = lo; i < hi; ++i){ start[i] = run; run += cnt[i]; }
    if (hi == NCOL && lo < NCOL) start[NCOL] = run;
}

// edges[p] = { row, f32_bits(val) }
__global__ void k_scatter(const int* __restrict__ rows, const int* __restrict__ cols,
                          const float* __restrict__ vals, const int* __restrict__ start,
                          int* __restrict__ cursor, uint2* __restrict__ edges){
    int e = blockIdx.x * 256 + threadIdx.x;
    if (e < NEDGE){
        int c = cols[e];
        int p = start[c] + atomicAdd(&cursor[c], 1);
        edges[p] = make_uint2((uint)rows[e], __builtin_bit_cast(uint, vals[e]));
    }
}

// ---------------- L-inf projection of W ----------------
__global__ void k_project(const float* __restrict__ W, ushort* __restrict__ Wp){
    int row = blockIdx.x * 4 + (threadIdx.x >> 6);
    int l = threadIdx.x & 63;
    const float* wr = W + row * MDIM;
    float w0 = wr[l], w1 = wr[l + 64];
    float a0 = fabsf(w0), a1 = fabsf(w1);
    float s = a0 + a1, mx = fmaxf(a0, a1);
    for (int off = 32; off; off >>= 1){
        s += __shfl_xor(s, off);
        mx = fmaxf(mx, __shfl_xor(mx, off));
    }
    if (s > FKAPPA){
        float tlo = 0.f, thi = mx;
        for (int it = 0; it < 48; ++it){
            float th = 0.5f * (tlo + thi);
            float f = fmaxf(a0 - th, 0.f) + fmaxf(a1 - th, 0.f);
            for (int off = 32; off; off >>= 1) f += __shfl_xor(f, off);
            if (f > FKAPPA) tlo = th; else thi = th;
        }
        float th = 0.5f * (tlo + thi);
        w0 = copysignf(fmaxf(a0 - th, 0.f), w0);
        w1 = copysignf(fmaxf(a1 - th, 0.f), w1);
    }
    Wp[row * MDIM + l] = f2bf(w0);
    Wp[row * MDIM + l + 64] = f2bf(w1);
}

__global__ void k_cvt(const float* __restrict__ src, ushort* __restrict__ dst){
    int i = blockIdx.x * 256 + threadIdx.x;
    if (i < MDIM * MDIM) dst[i] = f2bf(src[i]);
}

// ---------------- transposes f32 [128][N] <-> bf16 [N][128] ----------------
__global__ void k_tin(const float* __restrict__ X0, const float* __restrict__ U,
                      ushort* __restrict__ Xt, ushort* __restrict__ Ut){
    __shared__ ushort tile[128 * 66];
    const float* src = blockIdx.y ? U : X0;
    ushort* dst = blockIdx.y ? Ut : Xt;
    int c0 = blockIdx.x * 64;
    int t = threadIdx.x;
    for (int it = 0; it < 32; ++it){
        int le = it * 256 + t;
        int j = le & 63, m = le >> 6;
        int c = c0 + j;
        tile[m * 66 + j] = (c < NCOL) ? f2bf(src[m * NCOL + c]) : (ushort)0;
    }
    __syncthreads();
    for (int it = 0; it < 32; ++it){
        int le = it * 256 + t;
        int m = le & 127, jc = le >> 7;
        int c = c0 + jc;
        if (c < NCOL) dst[c * MDIM + m] = tile[m * 66 + jc];
    }
}

__global__ void k_tout(const ushort* __restrict__ Xt, float* __restrict__ out){
    __shared__ ushort tile[128 * 66];
    int c0 = blockIdx.x * 64;
    int t = threadIdx.x;
    for (int it = 0; it < 32; ++it){
        int le = it * 256 + t;
        int m = le & 127, jc = le >> 7;
        int c = c0 + jc;
        tile[m * 66 + jc] = (c < NCOL) ? Xt[c * MDIM + m] : (ushort)0;
    }
    __syncthreads();
    for (int it = 0; it < 32; ++it){
        int le = it * 256 + t;
        int j = le & 63, m = le >> 6;
        int c = c0 + j;
        if (c < NCOL) out[m * NCOL + c] = bf2f(tile[m * 66 + j]);
    }
}

__device__ __forceinline__ void fma8(float* acc, uint4 x, float v){
    acc[0] += v * bf2f((ushort)(x.x & 0xffffu)); acc[1] += v * bf2f((ushort)(x.x >> 16));
    acc[2] += v * bf2f((ushort)(x.y & 0xffffu)); acc[3] += v * bf2f((ushort)(x.y >> 16));
    acc[4] += v * bf2f((ushort)(x.z & 0xffffu)); acc[5] += v * bf2f((ushort)(x.z >> 16));
    acc[6] += v * bf2f((ushort)(x.w & 0xffffu)); acc[7] += v * bf2f((ushort)(x.w >> 16));
}

// ---------------- dense GEMM: Zt[c][m] = sum_k Mat[m][k] * Xt[c][k] ----------
// 16 cols/block (1250 blocks), 4 waves; wave w owns m-range [w*32, w*32+32).
// A-fragments and B-panel read directly from global (no LDS, no barrier).
__global__ __launch_bounds__(256, 4) void k_gemm(const ushort* __restrict__ Xt,
                        const ushort* __restrict__ Mat, ushort* __restrict__ Zt){
    int t = threadIdx.x;
    int w = t >> 6, l = t & 63;
    int c0 = blockIdx.x * 16;
    short8 afr[4];
    #pragma unroll
    for (int kc = 0; kc < 4; ++kc)
        afr[kc] = *(const short8*)(Xt + (size_t)(c0 + (l & 15)) * MDIM + kc * 32 + (l >> 4) * 8);
    short8 bfr[2][4];
    #pragma unroll
    for (int mt = 0; mt < 2; ++mt){
        int m = w * 32 + mt * 16 + (l & 15);
        #pragma unroll
        for (int kc = 0; kc < 4; ++kc)
            bfr[mt][kc] = *(const short8*)(Mat + m * MDIM + kc * 32 + (l >> 4) * 8);
    }
    #pragma unroll
    for (int mt = 0; mt < 2; ++mt){
        int m = w * 32 + mt * 16 + (l & 15);
        f32x4 a4 = {0.f, 0.f, 0.f, 0.f};
        #pragma unroll
        for (int kc = 0; kc < 4; ++kc)
            a4 = __builtin_amdgcn_mfma_f32_16x16x32_bf16(afr[kc], bfr[mt][kc], a4, 0, 0, 0);
        int cb = c0 + ((l >> 4) << 2);
        #pragma unroll
        for (int q = 0; q < 4; ++q)
            Zt[(size_t)(cb + q) * MDIM + m] = f2bf(a4[q]);
    }
}

// ---------------- gather: out[c][:] = phi( sum_e val_e * Zt[row_e][:] + Bt[c][:] )
// Pure gather — no MFMA, no LDS, no barriers. 16 cols/block, 4 waves, 4 cols/wave.
// R7's proven 4-round (deg<=16) / 8-round (deg<=32) straight-line blocks.
// MODE 0: raw write (Bt setup). MODE 1: bias+relu (coalesced uint4 Bt read).
template<int MODE>
__global__ __launch_bounds__(256, 6) void k_gather(const ushort* __restrict__ Zt,
                        const ushort* __restrict__ Bt, ushort* __restrict__ outp,
                        const int* __restrict__ start, const uint2* __restrict__ edges){
    int t = threadIdx.x;
    int w = t >> 6, l = t & 63;
    int c0 = blockIdx.x * 16;
    int g = l >> 4;     // edge slot within group-of-4
    int sub = l & 15;   // 16B chunk within 256B row

    int sa[5];
    #pragma unroll
    for (int i = 0; i < 5; ++i) sa[i] = start[c0 + w * 4 + i];

    uint2 myv[4];
    #pragma unroll
    for (int jj = 0; jj < 4; ++jj){
        int s = sa[jj], e = sa[jj + 1];
        int idx = (e > s) ? min(s + l, e - 1) : 0;
        myv[jj] = edges[idx];
    }

    #pragma unroll
    for (int jj = 0; jj < 4; ++jj){
        int s = sa[jj], e = sa[jj + 1];
        int d = e - s;
        float acc[8] = {0.f,0.f,0.f,0.f,0.f,0.f,0.f,0.f};
        if (d > 0){
            uint2 my = myv[jj];
            if (d <= 16){
                int r[4]; float v[4];
                #pragma unroll
                for (int b = 0; b < 4; ++b){
                    int slot = b * 4 + g;
                    int sel = min(slot, d - 1);
                    r[b] = __shfl((int)my.x, sel);
                    float vt = __builtin_bit_cast(float, __shfl((int)my.y, sel));
                    v[b] = (slot < d) ? vt : 0.f;
                }
                uint4 x[4];
                #pragma unroll
                for (int b = 0; b < 4; ++b)
                    x[b] = *(const uint4*)(Zt + (size_t)(uint)r[b] * MDIM + sub * 8);
                #pragma unroll
                for (int b = 0; b < 4; ++b) fma8(acc, x[b], v[b]);
            } else {
                int r[8]; float v[8];
                #pragma unroll
                for (int b = 0; b < 8; ++b){
                    int slot = b * 4 + g;
                    int sel = min(slot, min(d, 64) - 1);
                    r[b] = __shfl((int)my.x, sel);
                    float vt = __builtin_bit_cast(float, __shfl((int)my.y, sel));
                    v[b] = (slot < d) ? vt : 0.f;
                }
                uint4 x[8];
                #pragma unroll
                for (int b = 0; b < 8; ++b)
                    x[b] = *(const uint4*)(Zt + (size_t)(uint)r[b] * MDIM + sub * 8);
                #pragma unroll
                for (int b = 0; b < 8; ++b) fma8(acc, x[b], v[b]);
                if (d > 32){
                    for (int k2 = s + 32; k2 < e; k2 += 4){
                        int ke = k2 + g;
                        uint2 p = edges[min(ke, e - 1)];
                        float vv = (ke < e) ? __builtin_bit_cast(float, p.y) : 0.f;
                        uint4 xx = *(const uint4*)(Zt + (size_t)p.x * MDIM + sub * 8);
                        fma8(acc, xx, vv);
                    }
                }
            }
        }
        #pragma unroll
        for (int i = 0; i < 8; ++i){
            acc[i] += __shfl_xor(acc[i], 16);
            acc[i] += __shfl_xor(acc[i], 32);
        }
        int c = c0 + w * 4 + jj;
        if (l < 16){
            uint4 pk;
            if (MODE == 1){
                uint4 bt = *(const uint4*)(Bt + (size_t)c * MDIM + sub * 8);
                pk.x = pack2(fmaxf(acc[0] + bf2f((ushort)(bt.x & 0xffffu)), 0.f),
                             fmaxf(acc[1] + bf2f((ushort)(bt.x >> 16)), 0.f));
                pk.y = pack2(fmaxf(acc[2] + bf2f((ushort)(bt.y & 0xffffu)), 0.f),
                             fmaxf(acc[3] + bf2f((ushort)(bt.y >> 16)), 0.f));
                pk.z = pack2(fmaxf(acc[4] + bf2f((ushort)(bt.z & 0xffffu)), 0.f),
                             fmaxf(acc[5] + bf2f((ushort)(bt.z >> 16)), 0.f));
                pk.w = pack2(fmaxf(acc[6] + bf2f((ushort)(bt.w & 0xffffu)), 0.f),
                             fmaxf(acc[7] + bf2f((ushort)(bt.w >> 16)), 0.f));
            } else {
                pk.x = pack2(acc[0], acc[1]);
                pk.y = pack2(acc[2], acc[3]);
                pk.z = pack2(acc[4], acc[5]);
                pk.w = pack2(acc[6], acc[7]);
            }
            *(uint4*)(outp + (size_t)c * MDIM + sub * 8) = pk;
        }
    }
}

extern "C" void kernel_launch(void* const* d_in, const int* in_sizes, int n_in,
                              void* d_out, int out_size, void* d_ws, size_t ws_size,
                              hipStream_t stream){
    const float* X0 = (const float*)d_in[0];
    const float* U  = (const float*)d_in[1];
    const float* W  = (const float*)d_in[2];
    const float* Om = (const float*)d_in[3];
    const float* Av = (const float*)d_in[4];
    const int*   Ar = (const int*)d_in[5];
    const int*   Ac = (const int*)d_in[6];
    (void)in_sizes; (void)n_in; (void)out_size; (void)ws_size;

    char* ws = (char*)d_ws;
    size_t off = 0;
    auto alloc = [&](size_t bytes) -> char* {
        char* p = ws + off;
        off += (bytes + 255) & ~(size_t)255;
        return p;
    };
    int*    start = (int*)alloc((NCOL + 1) * 4);        //  80 KB
    uint2*  edges = (uint2*)alloc(NEDGE * 8);           //  2.56 MB
    ushort* Wp    = (ushort*)alloc(MDIM * MDIM * 2);    //  32 KB
    ushort* Omb   = (ushort*)alloc(MDIM * MDIM * 2);    //  32 KB
    ushort* Xb    = (ushort*)alloc(NCOL * MDIM * 2);    //  5.12 MB  (state X)
    ushort* Z     = (ushort*)alloc(NCOL * MDIM * 2);    //  5.12 MB  (Z = (Wp@X)^T)
    ushort* BtBF  = (ushort*)alloc(NCOL * MDIM * 2);    //  5.12 MB

    // cnt/cursor live in Z's space (dead before first k_gemm writes Z)
    int* cnt    = (int*)Z;
    int* cursor = cnt + NCOL;

    // d_out hosts Ut until k_tout overwrites everything
    ushort* Ut = (ushort*)d_out;

    k_zero<<<(2 * NCOL + 255) / 256, 256, 0, stream>>>(cnt);
    k_hist<<<(NEDGE + 255) / 256, 256, 0, stream>>>(Ac, cnt);
    k_scan<<<1, 256, 0, stream>>>(cnt, start);
    k_scatter<<<(NEDGE + 255) / 256, 256, 0, stream>>>(Ar, Ac, Av, start, cursor, edges);
    k_project<<<32, 256, 0, stream>>>(W, Wp);
    k_cvt<<<64, 256, 0, stream>>>(Om, Omb);
    k_tin<<<dim3(313, 2), 256, 0, stream>>>(X0, U, Xb, Ut);

    // Bt = ((Omega_1 @ U) @ A)^T : GEMM then gather (raw)
    k_gemm<<<1250, 256, 0, stream>>>(Ut, Omb, Z);
    k_gather<0><<<1250, 256, 0, stream>>>(Z, nullptr, BtBF, start, edges);

    // 30 iterations: Z = (Wp@X)^T ; X = relu(gather(Z) + Bt)
    for (int i = 0; i < NITER; ++i){
        k_gemm<<<1250, 256, 0, stream>>>(Xb, Wp, Z);
        k_gather<1><<<1250, 256, 0, stream>>>(Z, BtBF, Xb, start, edges);
    }
    k_tout<<<313, 256, 0, stream>>>(Xb, (float*)d_out);
}

// Round 12
// 656.986 us; speedup vs baseline: 1.5691x; 1.5691x over previous
//
#include <hip/hip_runtime.h>

#define MDIM 128
#define NCOL 20000
#define NEDGE 320000
#define NITER 30
#define FKAPPA 0.99f

typedef unsigned int uint;
typedef unsigned short ushort;
typedef __attribute__((ext_vector_type(8))) short short8;
typedef __attribute__((ext_vector_type(4))) float f32x4;

__device__ __forceinline__ float bf2f(ushort b){
    uint u = ((uint)b) << 16;
    return __builtin_bit_cast(float, u);
}
__device__ __forceinline__ ushort f2bf(float f){
    uint u = __builtin_bit_cast(uint, f);
    uint r = (u + 0x7fffu + ((u >> 16) & 1u)) >> 16;
    return (ushort)r;
}

// ---------------- CSC build ----------------
__global__ void k_zero(int* __restrict__ p){
    int i = blockIdx.x * 256 + threadIdx.x;
    if (i < 2 * NCOL) p[i] = 0;
}

__global__ void k_hist(const int* __restrict__ cols, int* __restrict__ cnt){
    int e = blockIdx.x * 256 + threadIdx.x;
    if (e < NEDGE) atomicAdd(&cnt[cols[e]], 1);
}

__global__ void k_scan(const int* __restrict__ cnt, int* __restrict__ start){
    __shared__ int lds[256];
    const int SEG = (NCOL + 255) / 256; // 79
    int t = threadIdx.x;
    int lo = t * SEG;
    int hi = min(lo + SEG, NCOL);
    int s = 0;
    for (int i = lo; i < hi; ++i) s += cnt[i];
    lds[t] = s;
    __syncthreads();
    for (int off = 1; off < 256; off <<= 1){
        int v = (t >= off) ? lds[t - off] : 0;
        __syncthreads();
        lds[t] += v;
        __syncthreads();
    }
    int run = (t > 0) ? lds[t - 1] : 0;
    for (int i = lo; i < hi; ++i){ start[i] = run; run += cnt[i]; }
    if (hi == NCOL && lo < NCOL) start[NCOL] = run;
}

// edges[p] = { row, f32_bits(val) }
__global__ void k_scatter(const int* __restrict__ rows, const int* __restrict__ cols,
                          const float* __restrict__ vals, const int* __restrict__ start,
                          int* __restrict__ cursor, uint2* __restrict__ edges){
    int e = blockIdx.x * 256 + threadIdx.x;
    if (e < NEDGE){
        int c = cols[e];
        int p = start[c] + atomicAdd(&cursor[c], 1);
        edges[p] = make_uint2((uint)rows[e], __builtin_bit_cast(uint, vals[e]));
    }
}

// ---------------- L-inf projection of W ----------------
__global__ void k_project(const float* __restrict__ W, ushort* __restrict__ Wp){
    int row = blockIdx.x * 4 + (threadIdx.x >> 6);
    int l = threadIdx.x & 63;
    const float* wr = W + row * MDIM;
    float w0 = wr[l], w1 = wr[l + 64];
    float a0 = fabsf(w0), a1 = fabsf(w1);
    float s = a0 + a1, mx = fmaxf(a0, a1);
    for (int off = 32; off; off >>= 1){
        s += __shfl_xor(s, off);
        mx = fmaxf(mx, __shfl_xor(mx, off));
    }
    if (s > FKAPPA){
        float tlo = 0.f, thi = mx;
        for (int it = 0; it < 48; ++it){
            float th = 0.5f * (tlo + thi);
            float f = fmaxf(a0 - th, 0.f) + fmaxf(a1 - th, 0.f);
            for (int off = 32; off; off >>= 1) f += __shfl_xor(f, off);
            if (f > FKAPPA) tlo = th; else thi = th;
        }
        float th = 0.5f * (tlo + thi);
        w0 = copysignf(fmaxf(a0 - th, 0.f), w0);
        w1 = copysignf(fmaxf(a1 - th, 0.f), w1);
    }
    Wp[row * MDIM + l] = f2bf(w0);
    Wp[row * MDIM + l + 64] = f2bf(w1);
}

__global__ void k_cvt(const float* __restrict__ src, ushort* __restrict__ dst){
    int i = blockIdx.x * 256 + threadIdx.x;
    if (i < MDIM * MDIM) dst[i] = f2bf(src[i]);
}

// ---------------- transposes f32 [128][N] <-> bf16 [N][128] ----------------
__global__ void k_tin(const float* __restrict__ X0, const float* __restrict__ U,
                      ushort* __restrict__ Xt, ushort* __restrict__ Ut){
    __shared__ ushort tile[128 * 66];
    const float* src = blockIdx.y ? U : X0;
    ushort* dst = blockIdx.y ? Ut : Xt;
    int c0 = blockIdx.x * 64;
    int t = threadIdx.x;
    for (int it = 0; it < 32; ++it){
        int le = it * 256 + t;
        int j = le & 63, m = le >> 6;
        int c = c0 + j;
        tile[m * 66 + j] = (c < NCOL) ? f2bf(src[m * NCOL + c]) : (ushort)0;
    }
    __syncthreads();
    for (int it = 0; it < 32; ++it){
        int le = it * 256 + t;
        int m = le & 127, jc = le >> 7;
        int c = c0 + jc;
        if (c < NCOL) dst[c * MDIM + m] = tile[m * 66 + jc];
    }
}

__global__ void k_tout(const ushort* __restrict__ Xt, float* __restrict__ out){
    __shared__ ushort tile[128 * 66];
    int c0 = blockIdx.x * 64;
    int t = threadIdx.x;
    for (int it = 0; it < 32; ++it){
        int le = it * 256 + t;
        int m = le & 127, jc = le >> 7;
        int c = c0 + jc;
        tile[m * 66 + jc] = (c < NCOL) ? Xt[c * MDIM + m] : (ushort)0;
    }
    __syncthreads();
    for (int it = 0; it < 32; ++it){
        int le = it * 256 + t;
        int j = le & 63, m = le >> 6;
        int c = c0 + j;
        if (c < NCOL) out[m * NCOL + c] = bf2f(tile[m * 66 + j]);
    }
}

__device__ __forceinline__ void fma8(float* acc, uint4 x, float v){
    acc[0] += v * bf2f((ushort)(x.x & 0xffffu)); acc[1] += v * bf2f((ushort)(x.x >> 16));
    acc[2] += v * bf2f((ushort)(x.y & 0xffffu)); acc[3] += v * bf2f((ushort)(x.y >> 16));
    acc[4] += v * bf2f((ushort)(x.z & 0xffffu)); acc[5] += v * bf2f((ushort)(x.z >> 16));
    acc[6] += v * bf2f((ushort)(x.w & 0xffffu)); acc[7] += v * bf2f((ushort)(x.w >> 16));
}

// ---------------- fused iteration (R7 structure + early Bt prefetch) --------
// out[c][m] = phi( sum_k (X@A)^T[c][k] * Mat[m][k] + Bt[c][m] )
// 16 columns per block (1250 blocks), 4 waves. Per column: ONE straight-line
// guarded block (4 loads if deg<=16, 8 loads if deg<=32, all issued before
// any FMA; clamped slots re-read the last row -> L1 hit, v=0 -> no traffic).
// Edge descriptors for all 4 columns preloaded wave-wide at entry.
// Bt values prefetched into registers BEFORE the barrier (latency hides under
// barrier + A-frag LDS reads + MFMAs instead of stalling the epilogue).
template<int MODE>
__global__ __launch_bounds__(256, 4) void k_fused(const ushort* __restrict__ Xt_in,
                        const ushort* __restrict__ Mat,
                        const ushort* __restrict__ Bt,
                        ushort* __restrict__ outp,
                        const int* __restrict__ start,
                        const uint2* __restrict__ edges){
    __shared__ alignas(16) char GL[4 * 1024];  // G[16][128] bf16, XOR-swizzled rows
    int t = threadIdx.x;
    int w = t >> 6, l = t & 63;
    int c0 = blockIdx.x * 16;
    int g = l >> 4;     // edge slot within group-of-4
    int sub = l & 15;   // 16B chunk within 256B row

    // start[] values for this wave's 4 columns (uniform -> SGPRs)
    int sa[5];
    #pragma unroll
    for (int i = 0; i < 5; ++i) sa[i] = start[c0 + w * 4 + i];

    // preload edge descriptor vectors for all 4 columns (4 loads in flight)
    uint2 myv[4];
    #pragma unroll
    for (int jj = 0; jj < 4; ++jj){
        int s = sa[jj], e = sa[jj + 1];
        int idx = (e > s) ? min(s + l, e - 1) : 0;
        myv[jj] = edges[idx];
    }

    #pragma unroll
    for (int jj = 0; jj < 4; ++jj){
        int s = sa[jj], e = sa[jj + 1];
        int d = e - s;
        float acc[8] = {0.f,0.f,0.f,0.f,0.f,0.f,0.f,0.f};
        if (d > 0){
            uint2 my = myv[jj];
            if (d <= 16){
                // 16-slot straight-line block: 4 loads in flight
                int r[4]; float v[4];
                #pragma unroll
                for (int b = 0; b < 4; ++b){
                    int slot = b * 4 + g;
                    int sel = min(slot, d - 1);
                    r[b] = __shfl((int)my.x, sel);
                    float vt = __builtin_bit_cast(float, __shfl((int)my.y, sel));
                    v[b] = (slot < d) ? vt : 0.f;
                }
                uint4 x[4];
                #pragma unroll
                for (int b = 0; b < 4; ++b)
                    x[b] = *(const uint4*)(Xt_in + (size_t)(uint)r[b] * 128 + sub * 8);
                #pragma unroll
                for (int b = 0; b < 4; ++b) fma8(acc, x[b], v[b]);
            } else {
                // 32-slot straight-line block: 8 loads in flight
                int r[8]; float v[8];
                #pragma unroll
                for (int b = 0; b < 8; ++b){
                    int slot = b * 4 + g;
                    int sel = min(slot, min(d, 64) - 1);
                    r[b] = __shfl((int)my.x, sel);
                    float vt = __builtin_bit_cast(float, __shfl((int)my.y, sel));
                    v[b] = (slot < d) ? vt : 0.f;
                }
                uint4 x[8];
                #pragma unroll
                for (int b = 0; b < 8; ++b)
                    x[b] = *(const uint4*)(Xt_in + (size_t)(uint)r[b] * 128 + sub * 8);
                #pragma unroll
                for (int b = 0; b < 8; ++b) fma8(acc, x[b], v[b]);
                // rare remainder: degree > 32 (~2 columns in 20000)
                if (d > 32){
                    for (int k2 = s + 32; k2 < e; k2 += 4){
                        int ke = k2 + g;
                        uint2 p = edges[min(ke, e - 1)];
                        float vv = (ke < e) ? __builtin_bit_cast(float, p.y) : 0.f;
                        uint4 xx = *(const uint4*)(Xt_in + (size_t)p.x * 128 + sub * 8);
                        fma8(acc, xx, vv);
                    }
                }
            }
        }
        // reduce 4 groups
        #pragma unroll
        for (int i = 0; i < 8; ++i){
            acc[i] += __shfl_xor(acc[i], 16);
            acc[i] += __shfl_xor(acc[i], 32);
        }
        int j = w * 4 + jj;
        if (l < 16){
            uint4 pk;
            pk.x = (uint)f2bf(acc[0]) | ((uint)f2bf(acc[1]) << 16);
            pk.y = (uint)f2bf(acc[2]) | ((uint)f2bf(acc[3]) << 16);
            pk.z = (uint)f2bf(acc[4]) | ((uint)f2bf(acc[5]) << 16);
            pk.w = (uint)f2bf(acc[6]) | ((uint)f2bf(acc[7]) << 16);
            *(uint4*)(GL + ((j * 256 + sub * 16) ^ ((j & 7) << 4))) = pk;
        }
    }

    // keep Mat/Bt fragment loads out of the gather loop (register pressure)
    __builtin_amdgcn_sched_barrier(0);

    // Mat B-panel for this wave: rows [w*32, w*32+32), all k -> 8 short8 fragments
    short8 bfr[2][4];
    #pragma unroll
    for (int mt = 0; mt < 2; ++mt){
        int m = w * 32 + mt * 16 + (l & 15);
        #pragma unroll
        for (int kc = 0; kc < 4; ++kc)
            bfr[mt][kc] = *(const short8*)(Mat + m * MDIM + kc * 32 + (l >> 4) * 8);
    }

    // Bt prefetch: this thread's 8 epilogue values, issued before the barrier
    // (c = c0 + (l>>4)*4 + q ; m = w*32 + mt*16 + (l&15)) — matches epilogue map
    float btv[2][4];
    if (MODE == 1){
        #pragma unroll
        for (int mt = 0; mt < 2; ++mt){
            int m = w * 32 + mt * 16 + (l & 15);
            #pragma unroll
            for (int q = 0; q < 4; ++q){
                int c = c0 + ((l >> 4) << 2) + q;
                btv[mt][q] = bf2f(Bt[(size_t)c * MDIM + m]);
            }
        }
    }
    __syncthreads();

    // GEMM phase: out[16 x 128] = G * Mat^T ; wave w owns m-range [w*32, w*32+32)
    {
        int arow = l & 15;
        int klane = (l >> 4) * 16;
        int asw = (arow & 7) << 4;
        short8 afr[4];
        #pragma unroll
        for (int kc = 0; kc < 4; ++kc)
            afr[kc] = *(const short8*)(GL + ((arow * 256 + kc * 64 + klane) ^ asw));
        #pragma unroll
        for (int mt = 0; mt < 2; ++mt){
            int m = w * 32 + mt * 16 + (l & 15);
            f32x4 acc4 = {0.f, 0.f, 0.f, 0.f};
            #pragma unroll
            for (int kc = 0; kc < 4; ++kc)
                acc4 = __builtin_amdgcn_mfma_f32_16x16x32_bf16(afr[kc], bfr[mt][kc], acc4, 0, 0, 0);
            int crow_base = c0 + ((l >> 4) << 2);
            #pragma unroll
            for (int q = 0; q < 4; ++q){
                int c = crow_base + q;
                float val = acc4[q];
                if (MODE == 1){
                    val = fmaxf(val + btv[mt][q], 0.f);
                }
                outp[c * MDIM + m] = f2bf(val);
            }
        }
    }
}

extern "C" void kernel_launch(void* const* d_in, const int* in_sizes, int n_in,
                              void* d_out, int out_size, void* d_ws, size_t ws_size,
                              hipStream_t stream){
    const float* X0 = (const float*)d_in[0];
    const float* U  = (const float*)d_in[1];
    const float* W  = (const float*)d_in[2];
    const float* Om = (const float*)d_in[3];
    const float* Av = (const float*)d_in[4];
    const int*   Ar = (const int*)d_in[5];
    const int*   Ac = (const int*)d_in[6];
    (void)in_sizes; (void)n_in; (void)out_size; (void)ws_size;

    char* ws = (char*)d_ws;
    size_t off = 0;
    auto alloc = [&](size_t bytes) -> char* {
        char* p = ws + off;
        off += (bytes + 255) & ~(size_t)255;
        return p;
    };
    int*    start = (int*)alloc((NCOL + 1) * 4);        //  80 KB
    uint2*  edges = (uint2*)alloc(NEDGE * 8);           //  2.56 MB
    ushort* Wp    = (ushort*)alloc(MDIM * MDIM * 2);    //  32 KB
    ushort* Omb   = (ushort*)alloc(MDIM * MDIM * 2);    //  32 KB
    ushort* P0    = (ushort*)alloc(NCOL * MDIM * 2);    //  5.12 MB

    // cnt/cursor live in P0's space (dead before k_tin writes it)
    int* cnt    = (int*)P0;
    int* cursor = cnt + NCOL;

    // d_out (10.24 MB f32) hosts P1 + Bt until the final transpose
    ushort* P1   = (ushort*)d_out;
    ushort* BtBF = (ushort*)((char*)d_out + NCOL * MDIM * 2);

    k_zero<<<(2 * NCOL + 255) / 256, 256, 0, stream>>>(cnt);
    k_hist<<<(NEDGE + 255) / 256, 256, 0, stream>>>(Ac, cnt);
    k_scan<<<1, 256, 0, stream>>>(cnt, start);
    k_scatter<<<(NEDGE + 255) / 256, 256, 0, stream>>>(Ar, Ac, Av, start, cursor, edges);
    k_project<<<32, 256, 0, stream>>>(W, Wp);
    k_cvt<<<64, 256, 0, stream>>>(Om, Omb);
    k_tin<<<dim3(313, 2), 256, 0, stream>>>(X0, U, P0, P1);
    // Bt = ((Omega_1 @ U) @ A)^T, stored bf16
    k_fused<0><<<1250, 256, 0, stream>>>(P1, Omb, nullptr, BtBF, start, edges);
    const ushort* cur = P0; ushort* nxt = P1;
    for (int i = 0; i < NITER; ++i){
        k_fused<1><<<1250, 256, 0, stream>>>(cur, Wp, BtBF, nxt, start, edges);
        ushort* tmp = (ushort*)cur; cur = nxt; nxt = tmp;
    }
    // NITER even -> cur == P0 (ws); k_tout overwrites all of d_out (P1/Bt dead)
    k_tout<<<313, 256, 0, stream>>>(cur, (float*)d_out);
}

// Round 13
// 591.312 us; speedup vs baseline: 1.7433x; 1.1111x over previous
//
#include <hip/hip_runtime.h>

#define MDIM 128
#define NCOL 20000
#define NEDGE 320000
#define NITER 30
#define FKAPPA 0.99f

typedef unsigned int uint;
typedef unsigned short ushort;
typedef __attribute__((ext_vector_type(8))) short short8;
typedef __attribute__((ext_vector_type(4))) float f32x4;

__device__ __forceinline__ float bf2f(ushort b){
    uint u = ((uint)b) << 16;
    return __builtin_bit_cast(float, u);
}
__device__ __forceinline__ ushort f2bf(float f){
    uint u = __builtin_bit_cast(uint, f);
    uint r = (u + 0x7fffu + ((u >> 16) & 1u)) >> 16;
    return (ushort)r;
}

// ---------------- CSC build ----------------
__global__ void k_zero(int* __restrict__ p){
    int i = blockIdx.x * 256 + threadIdx.x;
    if (i < 2 * NCOL) p[i] = 0;
}

__global__ void k_hist(const int* __restrict__ cols, int* __restrict__ cnt){
    int e = blockIdx.x * 256 + threadIdx.x;
    if (e < NEDGE) atomicAdd(&cnt[cols[e]], 1);
}

__global__ void k_scan(const int* __restrict__ cnt, int* __restrict__ start){
    __shared__ int lds[256];
    const int SEG = (NCOL + 255) / 256; // 79
    int t = threadIdx.x;
    int lo = t * SEG;
    int hi = min(lo + SEG, NCOL);
    int s = 0;
    for (int i = lo; i < hi; ++i) s += cnt[i];
    lds[t] = s;
    __syncthreads();
    for (int off = 1; off < 256; off <<= 1){
        int v = (t >= off) ? lds[t - off] : 0;
        __syncthreads();
        lds[t] += v;
        __syncthreads();
    }
    int run = (t > 0) ? lds[t - 1] : 0;
    for (int i = lo; i < hi; ++i){ start[i] = run; run += cnt[i]; }
    if (hi == NCOL && lo < NCOL) start[NCOL] = run;
}

// edges[p] = { row, f32_bits(val) }
__global__ void k_scatter(const int* __restrict__ rows, const int* __restrict__ cols,
                          const float* __restrict__ vals, const int* __restrict__ start,
                          int* __restrict__ cursor, uint2* __restrict__ edges){
    int e = blockIdx.x * 256 + threadIdx.x;
    if (e < NEDGE){
        int c = cols[e];
        int p = start[c] + atomicAdd(&cursor[c], 1);
        edges[p] = make_uint2((uint)rows[e], __builtin_bit_cast(uint, vals[e]));
    }
}

// ---------------- L-inf projection of W ----------------
__global__ void k_project(const float* __restrict__ W, ushort* __restrict__ Wp){
    int row = blockIdx.x * 4 + (threadIdx.x >> 6);
    int l = threadIdx.x & 63;
    const float* wr = W + row * MDIM;
    float w0 = wr[l], w1 = wr[l + 64];
    float a0 = fabsf(w0), a1 = fabsf(w1);
    float s = a0 + a1, mx = fmaxf(a0, a1);
    for (int off = 32; off; off >>= 1){
        s += __shfl_xor(s, off);
        mx = fmaxf(mx, __shfl_xor(mx, off));
    }
    if (s > FKAPPA){
        float tlo = 0.f, thi = mx;
        for (int it = 0; it < 48; ++it){
            float th = 0.5f * (tlo + thi);
            float f = fmaxf(a0 - th, 0.f) + fmaxf(a1 - th, 0.f);
            for (int off = 32; off; off >>= 1) f += __shfl_xor(f, off);
            if (f > FKAPPA) tlo = th; else thi = th;
        }
        float th = 0.5f * (tlo + thi);
        w0 = copysignf(fmaxf(a0 - th, 0.f), w0);
        w1 = copysignf(fmaxf(a1 - th, 0.f), w1);
    }
    Wp[row * MDIM + l] = f2bf(w0);
    Wp[row * MDIM + l + 64] = f2bf(w1);
}

__global__ void k_cvt(const float* __restrict__ src, ushort* __restrict__ dst){
    int i = blockIdx.x * 256 + threadIdx.x;
    if (i < MDIM * MDIM) dst[i] = f2bf(src[i]);
}

// ---------------- transposes f32 [128][N] <-> bf16 [N][128] ----------------
__global__ void k_tin(const float* __restrict__ X0, const float* __restrict__ U,
                      ushort* __restrict__ Xt, ushort* __restrict__ Ut){
    __shared__ ushort tile[128 * 66];
    const float* src = blockIdx.y ? U : X0;
    ushort* dst = blockIdx.y ? Ut : Xt;
    int c0 = blockIdx.x * 64;
    int t = threadIdx.x;
    for (int it = 0; it < 32; ++it){
        int le = it * 256 + t;
        int j = le & 63, m = le >> 6;
        int c = c0 + j;
        tile[m * 66 + j] = (c < NCOL) ? f2bf(src[m * NCOL + c]) : (ushort)0;
    }
    __syncthreads();
    for (int it = 0; it < 32; ++it){
        int le = it * 256 + t;
        int m = le & 127, jc = le >> 7;
        int c = c0 + jc;
        if (c < NCOL) dst[c * MDIM + m] = tile[m * 66 + jc];
    }
}

__global__ void k_tout(const ushort* __restrict__ Xt, float* __restrict__ out){
    __shared__ ushort tile[128 * 66];
    int c0 = blockIdx.x * 64;
    int t = threadIdx.x;
    for (int it = 0; it < 32; ++it){
        int le = it * 256 + t;
        int m = le & 127, jc = le >> 7;
        int c = c0 + jc;
        tile[m * 66 + jc] = (c < NCOL) ? Xt[c * MDIM + m] : (ushort)0;
    }
    __syncthreads();
    for (int it = 0; it < 32; ++it){
        int le = it * 256 + t;
        int j = le & 63, m = le >> 6;
        int c = c0 + j;
        if (c < NCOL) out[m * NCOL + c] = bf2f(tile[m * 66 + j]);
    }
}

__device__ __forceinline__ void fma8(float* acc, uint4 x, float v){
    acc[0] += v * bf2f((ushort)(x.x & 0xffffu)); acc[1] += v * bf2f((ushort)(x.x >> 16));
    acc[2] += v * bf2f((ushort)(x.y & 0xffffu)); acc[3] += v * bf2f((ushort)(x.y >> 16));
    acc[4] += v * bf2f((ushort)(x.z & 0xffffu)); acc[5] += v * bf2f((ushort)(x.z >> 16));
    acc[6] += v * bf2f((ushort)(x.w & 0xffffu)); acc[7] += v * bf2f((ushort)(x.w >> 16));
}

// ---------------- fused iteration ----------------
// out[c][m] = phi( sum_k (X@A)^T[c][k] * Mat[m][k] + Bt[c][m] )
// 16 columns per block (1250 blocks), 4 waves. Per column: ONE straight-line
// guarded block (4 loads if deg<=16, 8 loads if deg<=32, all issued before
// any FMA; clamped slots re-read the last row -> L1 hit, v=0 -> no traffic).
// Edge descriptors for all 4 columns preloaded wave-wide at entry.
template<int MODE>
__global__ __launch_bounds__(256, 5) void k_fused(const ushort* __restrict__ Xt_in,
                        const ushort* __restrict__ Mat,
                        const ushort* __restrict__ Bt,
                        ushort* __restrict__ outp,
                        const int* __restrict__ start,
                        const uint2* __restrict__ edges){
    __shared__ alignas(16) char GL[4 * 1024];  // G[16][128] bf16, XOR-swizzled rows
    int t = threadIdx.x;
    int w = t >> 6, l = t & 63;
    int c0 = blockIdx.x * 16;
    int g = l >> 4;     // edge slot within group-of-4
    int sub = l & 15;   // 16B chunk within 256B row

    // start[] values for this wave's 4 columns (uniform -> SGPRs)
    int sa[5];
    #pragma unroll
    for (int i = 0; i < 5; ++i) sa[i] = start[c0 + w * 4 + i];

    // preload edge descriptor vectors for all 4 columns (4 loads in flight)
    uint2 myv[4];
    #pragma unroll
    for (int jj = 0; jj < 4; ++jj){
        int s = sa[jj], e = sa[jj + 1];
        int idx = (e > s) ? min(s + l, e - 1) : 0;
        myv[jj] = edges[idx];
    }

    #pragma unroll
    for (int jj = 0; jj < 4; ++jj){
        int s = sa[jj], e = sa[jj + 1];
        int d = e - s;
        float acc[8] = {0.f,0.f,0.f,0.f,0.f,0.f,0.f,0.f};
        if (d > 0){
            uint2 my = myv[jj];
            if (d <= 16){
                // 16-slot straight-line block: 4 loads in flight
                int r[4]; float v[4];
                #pragma unroll
                for (int b = 0; b < 4; ++b){
                    int slot = b * 4 + g;
                    int sel = min(slot, d - 1);
                    r[b] = __shfl((int)my.x, sel);
                    float vt = __builtin_bit_cast(float, __shfl((int)my.y, sel));
                    v[b] = (slot < d) ? vt : 0.f;
                }
                uint4 x[4];
                #pragma unroll
                for (int b = 0; b < 4; ++b)
                    x[b] = *(const uint4*)(Xt_in + (size_t)(uint)r[b] * 128 + sub * 8);
                #pragma unroll
                for (int b = 0; b < 4; ++b) fma8(acc, x[b], v[b]);
            } else {
                // 32-slot straight-line block: 8 loads in flight
                int r[8]; float v[8];
                #pragma unroll
                for (int b = 0; b < 8; ++b){
                    int slot = b * 4 + g;
                    int sel = min(slot, min(d, 64) - 1);
                    r[b] = __shfl((int)my.x, sel);
                    float vt = __builtin_bit_cast(float, __shfl((int)my.y, sel));
                    v[b] = (slot < d) ? vt : 0.f;
                }
                uint4 x[8];
                #pragma unroll
                for (int b = 0; b < 8; ++b)
                    x[b] = *(const uint4*)(Xt_in + (size_t)(uint)r[b] * 128 + sub * 8);
                #pragma unroll
                for (int b = 0; b < 8; ++b) fma8(acc, x[b], v[b]);
                // rare remainder: degree > 32 (~2 columns in 20000)
                if (d > 32){
                    for (int k2 = s + 32; k2 < e; k2 += 4){
                        int ke = k2 + g;
                        uint2 p = edges[min(ke, e - 1)];
                        float vv = (ke < e) ? __builtin_bit_cast(float, p.y) : 0.f;
                        uint4 xx = *(const uint4*)(Xt_in + (size_t)p.x * 128 + sub * 8);
                        fma8(acc, xx, vv);
                    }
                }
            }
        }
        // reduce 4 groups
        #pragma unroll
        for (int i = 0; i < 8; ++i){
            acc[i] += __shfl_xor(acc[i], 16);
            acc[i] += __shfl_xor(acc[i], 32);
        }
        int j = w * 4 + jj;
        if (l < 16){
            uint4 pk;
            pk.x = (uint)f2bf(acc[0]) | ((uint)f2bf(acc[1]) << 16);
            pk.y = (uint)f2bf(acc[2]) | ((uint)f2bf(acc[3]) << 16);
            pk.z = (uint)f2bf(acc[4]) | ((uint)f2bf(acc[5]) << 16);
            pk.w = (uint)f2bf(acc[6]) | ((uint)f2bf(acc[7]) << 16);
            *(uint4*)(GL + ((j * 256 + sub * 16) ^ ((j & 7) << 4))) = pk;
        }
    }

    // keep Mat fragment loads out of the gather loop (register pressure)
    __builtin_amdgcn_sched_barrier(0);

    // Mat B-panel for this wave: rows [w*32, w*32+32), all k -> 8 short8 fragments
    short8 bfr[2][4];
    #pragma unroll
    for (int mt = 0; mt < 2; ++mt){
        int m = w * 32 + mt * 16 + (l & 15);
        #pragma unroll
        for (int kc = 0; kc < 4; ++kc)
            bfr[mt][kc] = *(const short8*)(Mat + m * MDIM + kc * 32 + (l >> 4) * 8);
    }
    __syncthreads();

    // GEMM phase: out[16 x 128] = G * Mat^T ; wave w owns m-range [w*32, w*32+32)
    {
        int arow = l & 15;
        int klane = (l >> 4) * 16;
        int asw = (arow & 7) << 4;
        short8 afr[4];
        #pragma unroll
        for (int kc = 0; kc < 4; ++kc)
            afr[kc] = *(const short8*)(GL + ((arow * 256 + kc * 64 + klane) ^ asw));
        #pragma unroll
        for (int mt = 0; mt < 2; ++mt){
            int m = w * 32 + mt * 16 + (l & 15);
            f32x4 acc4 = {0.f, 0.f, 0.f, 0.f};
            #pragma unroll
            for (int kc = 0; kc < 4; ++kc)
                acc4 = __builtin_amdgcn_mfma_f32_16x16x32_bf16(afr[kc], bfr[mt][kc], acc4, 0, 0, 0);
            int crow_base = c0 + ((l >> 4) << 2);
            #pragma unroll
            for (int q = 0; q < 4; ++q){
                int c = crow_base + q;
                float val = acc4[q];
                if (MODE == 1){
                    val += bf2f(Bt[c * MDIM + m]);
                    val = fmaxf(val, 0.f);
                }
                outp[c * MDIM + m] = f2bf(val);
            }
        }
    }
}

extern "C" void kernel_launch(void* const* d_in, const int* in_sizes, int n_in,
                              void* d_out, int out_size, void* d_ws, size_t ws_size,
                              hipStream_t stream){
    const float* X0 = (const float*)d_in[0];
    const float* U  = (const float*)d_in[1];
    const float* W  = (const float*)d_in[2];
    const float* Om = (const float*)d_in[3];
    const float* Av = (const float*)d_in[4];
    const int*   Ar = (const int*)d_in[5];
    const int*   Ac = (const int*)d_in[6];
    (void)in_sizes; (void)n_in; (void)out_size; (void)ws_size;

    char* ws = (char*)d_ws;
    size_t off = 0;
    auto alloc = [&](size_t bytes) -> char* {
        char* p = ws + off;
        off += (bytes + 255) & ~(size_t)255;
        return p;
    };
    int*    start = (int*)alloc((NCOL + 1) * 4);        //  80 KB
    uint2*  edges = (uint2*)alloc(NEDGE * 8);           //  2.56 MB
    ushort* Wp    = (ushort*)alloc(MDIM * MDIM * 2);    //  32 KB
    ushort* Omb   = (ushort*)alloc(MDIM * MDIM * 2);    //  32 KB
    ushort* P0    = (ushort*)alloc(NCOL * MDIM * 2);    //  5.12 MB

    // cnt/cursor live in P0's space (dead before k_tin writes it)
    int* cnt    = (int*)P0;
    int* cursor = cnt + NCOL;

    // d_out (10.24 MB f32) hosts P1 + Bt until the final transpose
    ushort* P1   = (ushort*)d_out;
    ushort* BtBF = (ushort*)((char*)d_out + NCOL * MDIM * 2);

    k_zero<<<(2 * NCOL + 255) / 256, 256, 0, stream>>>(cnt);
    k_hist<<<(NEDGE + 255) / 256, 256, 0, stream>>>(Ac, cnt);
    k_scan<<<1, 256, 0, stream>>>(cnt, start);
    k_scatter<<<(NEDGE + 255) / 256, 256, 0, stream>>>(Ar, Ac, Av, start, cursor, edges);
    k_project<<<32, 256, 0, stream>>>(W, Wp);
    k_cvt<<<64, 256, 0, stream>>>(Om, Omb);
    k_tin<<<dim3(313, 2), 256, 0, stream>>>(X0, U, P0, P1);
    // Bt = ((Omega_1 @ U) @ A)^T, stored bf16
    k_fused<0><<<1250, 256, 0, stream>>>(P1, Omb, nullptr, BtBF, start, edges);
    const ushort* cur = P0; ushort* nxt = P1;
    for (int i = 0; i < NITER; ++i){
        k_fused<1><<<1250, 256, 0, stream>>>(cur, Wp, BtBF, nxt, start, edges);
        ushort* tmp = (ushort*)cur; cur = nxt; nxt = tmp;
    }
    // NITER even -> cur == P0 (ws); k_tout overwrites all of d_out (P1/Bt dead)
    k_tout<<<313, 256, 0, stream>>>(cur, (float*)d_out);
}